// Round 1
// baseline (707.367 us; speedup 1.0000x reference)
//
#include <hip/hip_runtime.h>

typedef float nf4 __attribute__((ext_vector_type(4)));   // native vec for nontemporal builtins

// Problem constants
constexpr int Sdim = 2048;
constexpr int Bdim = 64;
constexpr int Hdim = 1024;
constexpr int NCHUNK = 32;   // s-chunks per b in K1 (64 s each, 16 s per wave)
constexpr int KS1 = 16;      // fc1 k-split: K=2048 -> slices of 128
constexpr int KS2 = 8;       // fc2 k-split: K=1024 -> slices of 128

// Workspace layout (float offsets). Total ~14.6 MiB.
constexpr int PM_OFF   = 0;                                 // 2048  partial max per (b,chunk)
constexpr int PL_OFF   = PM_OFF + Bdim * NCHUNK;            // 2048  partial l
constexpr int PACC_OFF = PL_OFF + Bdim * NCHUNK;            // 64*32*1024 partial weighted sums
constexpr int ATTN_OFF = PACC_OFF + Bdim * NCHUNK * Hdim;   // 64*1024 attn result
constexpr int XMID_OFF = ATTN_OFF + Bdim * Hdim;            // 64*1024 tanh(BN(fc1)) transposed [o][b]
constexpr int P1_OFF   = XMID_OFF + Bdim * Hdim;            // KS1*64*1024 fc1 k-partials
constexpr int P2_OFF   = P1_OFF + KS1 * Bdim * Hdim;        // KS2*64*1024 fc2 k-partials

// ---------------------------------------------------------------------------
// K1: one-pass attention with EXPLICIT double-buffered prefetch.
// Two disjoint register buffers (pair A = 2 s-rows, pair B = 2 s-rows).
// The next pair's 8 NT loads are issued in source order BEFORE the current
// pair's shuffle-reduce/exp/acc chain, so >=8KiB stays in flight per wave
// across the serial online-softmax math. This is the fix for the MLP collapse
// that kept k1 at ~25-40% of achievable HBM BW: previously va/vb were live
// until the end of the chain, so the compiler issued the next loads only
// after the acc update, exposing ~900cy of HBM latency per iteration.
// ---------------------------------------------------------------------------
__global__ __launch_bounds__(256) void k1_attn(const float* __restrict__ ctx,
                                               const float* __restrict__ key,
                                               const float* __restrict__ mask,
                                               float* __restrict__ ws,
                                               float* __restrict__ At) {
    const int chunk = blockIdx.x;    // 0..31
    const int b     = blockIdx.y;    // 0..63
    const int t     = threadIdx.x;
    const int lane  = t & 63;
    const int wave  = t >> 6;

    // key fragment: h = j*256 + lane*4 .. +3
    const nf4* key4 = (const nf4*)(key + (size_t)b * Hdim);
    nf4 kr[4];
#pragma unroll
    for (int j = 0; j < 4; ++j) kr[j] = key4[j * 64 + lane];

    nf4 acc[4];
#pragma unroll
    for (int j = 0; j < 4; ++j) acc[j] = (nf4)(0.f);
    float m = -1e30f, l = 0.f;

    const int s0 = chunk * 64 + wave * 16;
    // row s of this b starts at nf4 offset s*(Bdim*256) + b*256
    const nf4* cbase = (const nf4*)ctx + ((size_t)b << 8);

    // issue 8 NT loads for rows (sa, sa+1) into (va, vb)
    auto load2 = [&](nf4 (&va)[4], nf4 (&vb)[4], int sa) {
        const nf4* ca = cbase + (size_t)sa * (Bdim * 256);
        const nf4* cb = ca + (Bdim * 256);
#pragma unroll
        for (int j = 0; j < 4; ++j) va[j] = __builtin_nontemporal_load(&ca[j * 64 + lane]);
#pragma unroll
        for (int j = 0; j < 4; ++j) vb[j] = __builtin_nontemporal_load(&cb[j * 64 + lane]);
    };

    // dot + reduce + score stash + online-softmax update for rows (sa, sa+1)
    auto dopair = [&](nf4 (&va)[4], nf4 (&vb)[4], int sa) {
        float da = 0.f, db = 0.f;
#pragma unroll
        for (int j = 0; j < 4; ++j) {
            da += va[j].x * kr[j].x + va[j].y * kr[j].y + va[j].z * kr[j].z + va[j].w * kr[j].w;
            db += vb[j].x * kr[j].x + vb[j].y * kr[j].y + vb[j].z * kr[j].z + vb[j].w * kr[j].w;
        }
#pragma unroll
        for (int off = 32; off >= 1; off >>= 1) {
            da += __shfl_xor(da, off, 64);
            db += __shfl_xor(db, off, 64);
        }
        da += mask[b * Sdim + sa];
        db += mask[b * Sdim + sa + 1];
        if (lane == 0) {
            At[b * Sdim + sa]     = da;   // raw score stash
            At[b * Sdim + sa + 1] = db;
        }
        const float nm = fmaxf(m, fmaxf(da, db));
        const float sc = __expf(m - nm);
        const float wa = __expf(da - nm);
        const float wb = __expf(db - nm);
#pragma unroll
        for (int j = 0; j < 4; ++j)
            acc[j] = acc[j] * sc + va[j] * wa + vb[j] * wb;
        l = l * sc + wa + wb;
        m = nm;
    };

    nf4 A0[4], A1[4], B0[4], B1[4];
    load2(A0, A1, s0);                       // prologue: rows 0,1 in flight
#pragma unroll
    for (int i = 0; i < 4; ++i) {
        load2(B0, B1, s0 + 4 * i + 2);       // prefetch rows 4i+2,4i+3
        dopair(A0, A1, s0 + 4 * i);          // consume rows 4i,4i+1
        if (i < 3)
            load2(A0, A1, s0 + 4 * i + 4);   // prefetch rows 4i+4,4i+5
        dopair(B0, B1, s0 + 4 * i + 2);      // consume rows 4i+2,4i+3
    }

    // combine 4 waves
    __shared__ float lm[4], ll[4];
    __shared__ __align__(16) float lacc[4][1024];
    if (lane == 0) { lm[wave] = m; ll[wave] = l; }
    __syncthreads();
    const float M  = fmaxf(fmaxf(lm[0], lm[1]), fmaxf(lm[2], lm[3]));
    const float scw = __expf(m - M);   // wave-uniform
    nf4* lw = (nf4*)lacc[wave];
#pragma unroll
    for (int j = 0; j < 4; ++j)
        lw[j * 64 + lane] = acc[j] * scw;
    __syncthreads();

    const float L = ll[0] * __expf(lm[0] - M) + ll[1] * __expf(lm[1] - M)
                  + ll[2] * __expf(lm[2] - M) + ll[3] * __expf(lm[3] - M);
    const nf4* l4 = (const nf4*)lacc;   // [4][256] nf4
    nf4 r = l4[t];
#pragma unroll
    for (int wv = 1; wv < 4; ++wv)
        r += l4[wv * 256 + t];
    ((nf4*)(ws + PACC_OFF))[(b * NCHUNK + chunk) * 256 + t] = r;
    if (t == 0) {
        ws[PM_OFF + b * NCHUNK + chunk] = M;
        ws[PL_OFF + b * NCHUNK + chunk] = L;
    }
}

// ---------------------------------------------------------------------------
// K2: per-b merge of 32 chunk partials -> attn[b,:], and finalize At in place.
// ---------------------------------------------------------------------------
__global__ __launch_bounds__(256) void k2_final(float* __restrict__ ws,
                                                float* __restrict__ At) {
    const int b = blockIdx.x;
    const int t = threadIdx.x;

    float M = -1e30f;
#pragma unroll
    for (int c = 0; c < NCHUNK; ++c)
        M = fmaxf(M, ws[PM_OFF + b * NCHUNK + c]);
    float L = 0.f;
#pragma unroll
    for (int c = 0; c < NCHUNK; ++c)
        L += ws[PL_OFF + b * NCHUNK + c] * __expf(ws[PM_OFF + b * NCHUNK + c] - M);
    const float invL = 1.f / L;

    const nf4* pa = (const nf4*)(ws + PACC_OFF);
    nf4 r = (nf4)(0.f);
#pragma unroll
    for (int c = 0; c < NCHUNK; ++c) {
        const float e = __expf(ws[PM_OFF + b * NCHUNK + c] - M);
        r += pa[(b * NCHUNK + c) * 256 + t] * e;
    }
    r *= invL;
    ((nf4*)(ws + ATTN_OFF))[b * 256 + t] = r;

    // finalize At: 2048 floats per b = 512 float4, 2 per thread
    nf4* At4 = (nf4*)(At + b * Sdim);
#pragma unroll
    for (int k = 0; k < 2; ++k) {
        nf4 v = At4[t + k * 256];
        v.x = __expf(v.x - M) * invL;
        v.y = __expf(v.y - M) * invL;
        v.z = __expf(v.z - M) * invL;
        v.w = __expf(v.w - M) * invL;
        At4[t + k * 256] = v;
    }
}

// ---------------------------------------------------------------------------
// K3a: fc1 split-K GEMM. x = [attn | key] (virtual concat), w = fc1_w (1024x2048).
// Block: 64 b x 64 o tile, k-slice of 128. 4x4 register micro-tile per thread.
// Register-staged prefetch: chunk c+1's global loads issue right after chunk
// c's LDS write, hiding HBM latency under the 32-step FMA loop.
// ---------------------------------------------------------------------------
__global__ __launch_bounds__(256) void k3a_fc1(const float* __restrict__ attn,
                                               const float* __restrict__ key,
                                               const float* __restrict__ w,
                                               float* __restrict__ part) {
    const int obase = blockIdx.x * 64;
    const int kblk  = blockIdx.y;               // 0..KS1-1
    const int t  = threadIdx.x;
    const int bx = (t & 15) * 4;
    const int ox = (t >> 4) * 4;

    __shared__ __align__(16) float xs[32][68];
    __shared__ __align__(16) float wsh[32][68];

    float a[4][4];
#pragma unroll
    for (int i = 0; i < 4; ++i)
#pragma unroll
        for (int j = 0; j < 4; ++j) a[i][j] = 0.f;

    float xr[8], wr[8];
    auto stage_load = [&](int c) {
        const int i0 = kblk * 128 + c * 32;
        const float* src = (i0 < Hdim) ? (attn + i0) : (key + (i0 - Hdim));
#pragma unroll
        for (int j = 0; j < 8; ++j) {
            const int e = t + j * 256;
            const int k_l = e & 31, b_l = e >> 5;
            xr[j] = src[b_l * Hdim + k_l];
        }
#pragma unroll
        for (int j = 0; j < 8; ++j) {
            const int e = t + j * 256;
            const int k_l = e & 31, o_l = e >> 5;
            wr[j] = w[(size_t)(obase + o_l) * 2048 + i0 + k_l];
        }
    };

    stage_load(0);
    for (int c = 0; c < 4; ++c) {               // 4 chunks of 32 = slice 128
        __syncthreads();                        // LDS free from previous compute
#pragma unroll
        for (int j = 0; j < 8; ++j) {
            const int e = t + j * 256;
            xs[e & 31][e >> 5] = xr[j];
        }
#pragma unroll
        for (int j = 0; j < 8; ++j) {
            const int e = t + j * 256;
            wsh[e & 31][e >> 5] = wr[j];
        }
        if (c < 3) stage_load(c + 1);           // overlap next chunk's HBM latency
        __syncthreads();
#pragma unroll
        for (int k = 0; k < 32; ++k) {
            const float4 xv = *(const float4*)&xs[k][bx];
            const float4 wv = *(const float4*)&wsh[k][ox];
            a[0][0] += xv.x * wv.x; a[0][1] += xv.x * wv.y; a[0][2] += xv.x * wv.z; a[0][3] += xv.x * wv.w;
            a[1][0] += xv.y * wv.x; a[1][1] += xv.y * wv.y; a[1][2] += xv.y * wv.z; a[1][3] += xv.y * wv.w;
            a[2][0] += xv.z * wv.x; a[2][1] += xv.z * wv.y; a[2][2] += xv.z * wv.z; a[2][3] += xv.z * wv.w;
            a[3][0] += xv.w * wv.x; a[3][1] += xv.w * wv.y; a[3][2] += xv.w * wv.z; a[3][3] += xv.w * wv.w;
        }
    }
    float* p = part + (size_t)kblk * (Bdim * Hdim);
#pragma unroll
    for (int i = 0; i < 4; ++i)
        *(float4*)&p[(bx + i) * Hdim + obase + ox] = make_float4(a[i][0], a[i][1], a[i][2], a[i][3]);
}

// ---------------------------------------------------------------------------
// K3b: reduce fc1 partials + bias, BatchNorm (batch stats via 64-lane wave
// reduction: one wave = all 64 batch rows), tanh; store transposed [o][b].
// ---------------------------------------------------------------------------
__global__ __launch_bounds__(256) void k3b_bn(const float* __restrict__ p1,
                                              const float* __restrict__ fc1_b,
                                              const float* __restrict__ gamma,
                                              const float* __restrict__ beta,
                                              float* __restrict__ xmidT) {
    const int obase = blockIdx.x * 16;
    const int t  = threadIdx.x;
    const int b  = t & 63;
    const int ot = t >> 6;
    const int o0 = obase + ot * 4;

    float4 acc = ((const float4*)fc1_b)[o0 >> 2];
    const float4* p4 = (const float4*)p1;
#pragma unroll
    for (int k = 0; k < KS1; ++k) {
        float4 v = p4[k * (Bdim * Hdim / 4) + b * (Hdim / 4) + (o0 >> 2)];
        acc.x += v.x; acc.y += v.y; acc.z += v.z; acc.w += v.w;
    }
    const float4 g  = ((const float4*)gamma)[o0 >> 2];
    const float4 be = ((const float4*)beta)[o0 >> 2];
    const float xv[4] = {acc.x, acc.y, acc.z, acc.w};
    const float gv[4] = {g.x, g.y, g.z, g.w};
    const float bv[4] = {be.x, be.y, be.z, be.w};
#pragma unroll
    for (int q = 0; q < 4; ++q) {
        const float x = xv[q];
        float s1 = x, s2 = x * x;
#pragma unroll
        for (int off = 32; off >= 1; off >>= 1) {
            s1 += __shfl_xor(s1, off, 64);
            s2 += __shfl_xor(s2, off, 64);
        }
        const float mean = s1 * (1.f / 64.f);
        float var = s2 * (1.f / 64.f) - mean * mean;
        var = fmaxf(var, 0.f);
        const float inv = rsqrtf(var + 1e-5f);
        const float y = (x - mean) * inv * gv[q] + bv[q];
        xmidT[(o0 + q) * Bdim + b] = tanhf(y);
    }
}

// ---------------------------------------------------------------------------
// K4a: fc2 split-K GEMM. Input xmidT is [k][b] (transposed), w = fc2_w (1024x1024).
// Same register-staged prefetch as K3a.
// ---------------------------------------------------------------------------
__global__ __launch_bounds__(256) void k4a_fc2(const float* __restrict__ xmidT,
                                               const float* __restrict__ w,
                                               float* __restrict__ part) {
    const int obase = blockIdx.x * 64;
    const int kblk  = blockIdx.y;               // 0..KS2-1
    const int t  = threadIdx.x;
    const int bx = (t & 15) * 4;
    const int ox = (t >> 4) * 4;

    __shared__ __align__(16) float xs[32][68];
    __shared__ __align__(16) float wsh[32][68];

    float a[4][4];
#pragma unroll
    for (int i = 0; i < 4; ++i)
#pragma unroll
        for (int j = 0; j < 4; ++j) a[i][j] = 0.f;

    float xr[8], wr[8];
    auto stage_load = [&](int c) {
        const int i0 = kblk * 128 + c * 32;
#pragma unroll
        for (int j = 0; j < 8; ++j) {
            const int e = t + j * 256;
            const int k_l = e >> 6, b_l = e & 63;
            xr[j] = xmidT[(i0 + k_l) * Bdim + b_l];
        }
#pragma unroll
        for (int j = 0; j < 8; ++j) {
            const int e = t + j * 256;
            const int k_l = e & 31, o_l = e >> 5;
            wr[j] = w[(size_t)(obase + o_l) * Hdim + i0 + k_l];
        }
    };

    stage_load(0);
    for (int c = 0; c < 4; ++c) {
        __syncthreads();
#pragma unroll
        for (int j = 0; j < 8; ++j) {
            const int e = t + j * 256;
            xs[e >> 6][e & 63] = xr[j];
        }
#pragma unroll
        for (int j = 0; j < 8; ++j) {
            const int e = t + j * 256;
            wsh[e & 31][e >> 5] = wr[j];
        }
        if (c < 3) stage_load(c + 1);
        __syncthreads();
#pragma unroll
        for (int k = 0; k < 32; ++k) {
            const float4 xv = *(const float4*)&xs[k][bx];
            const float4 wv = *(const float4*)&wsh[k][ox];
            a[0][0] += xv.x * wv.x; a[0][1] += xv.x * wv.y; a[0][2] += xv.x * wv.z; a[0][3] += xv.x * wv.w;
            a[1][0] += xv.y * wv.x; a[1][1] += xv.y * wv.y; a[1][2] += xv.y * wv.z; a[1][3] += xv.y * wv.w;
            a[2][0] += xv.z * wv.x; a[2][1] += xv.z * wv.y; a[2][2] += xv.z * wv.z; a[2][3] += xv.z * wv.w;
            a[3][0] += xv.w * wv.x; a[3][1] += xv.w * wv.y; a[3][2] += xv.w * wv.z; a[3][3] += xv.w * wv.w;
        }
    }
    float* p = part + (size_t)kblk * (Bdim * Hdim);
#pragma unroll
    for (int i = 0; i < 4; ++i)
        *(float4*)&p[(bx + i) * Hdim + obase + ox] = make_float4(a[i][0], a[i][1], a[i][2], a[i][3]);
}

// ---------------------------------------------------------------------------
// K4b: reduce fc2 partials + bias -> final x output (coalesced).
// ---------------------------------------------------------------------------
__global__ __launch_bounds__(256) void k4b_out(const float* __restrict__ p2,
                                               const float* __restrict__ fc2_b,
                                               float* __restrict__ outx) {
    const int idx = blockIdx.x * 256 + threadIdx.x;   // 0..65535
    float v = fc2_b[idx & (Hdim - 1)];
#pragma unroll
    for (int k = 0; k < KS2; ++k) v += p2[k * (Bdim * Hdim) + idx];
    outx[idx] = v;
}

extern "C" void kernel_launch(void* const* d_in, const int* in_sizes, int n_in,
                              void* d_out, int out_size, void* d_ws, size_t ws_size,
                              hipStream_t stream) {
    const float* ctx    = (const float*)d_in[0];
    const float* key    = (const float*)d_in[1];
    const float* mask   = (const float*)d_in[2];
    const float* fc1_w  = (const float*)d_in[3];
    const float* fc1_b  = (const float*)d_in[4];
    const float* gamma  = (const float*)d_in[5];
    const float* beta   = (const float*)d_in[6];
    const float* fc2_w  = (const float*)d_in[7];
    const float* fc2_b  = (const float*)d_in[8];

    float* outx = (float*)d_out;               // (64,1024)
    float* At   = outx + Bdim * Hdim;          // (64,2048)
    float* ws   = (float*)d_ws;

    k1_attn<<<dim3(NCHUNK, Bdim), 256, 0, stream>>>(ctx, key, mask, ws, At);
    k2_final<<<Bdim, 256, 0, stream>>>(ws, At);
    k3a_fc1<<<dim3(Hdim / 64, KS1), 256, 0, stream>>>(ws + ATTN_OFF, key, fc1_w, ws + P1_OFF);
    k3b_bn<<<Hdim / 16, 256, 0, stream>>>(ws + P1_OFF, fc1_b, gamma, beta, ws + XMID_OFF);
    k4a_fc2<<<dim3(Hdim / 64, KS2), 256, 0, stream>>>(ws + XMID_OFF, fc2_w, ws + P2_OFF);
    k4b_out<<<Bdim * Hdim / 256, 256, 0, stream>>>(ws + P2_OFF, fc2_b, outx);
}